// Round 7
// baseline (2007.132 us; speedup 1.0000x reference)
//
#include <hip/hip_runtime.h>
#include <math.h>

// Problem dims (fixed by the reference)
#define BB 64
#define TT 1024
#define EE 256
#define HH 512
#define OO 32000
#define KDIM 768   // H+E

typedef float f32x2 __attribute__((ext_vector_type(2)));
typedef unsigned long long u64;

__device__ __forceinline__ f32x2 mk2(float a, float b) { f32x2 r; r.x = a; r.y = b; return r; }

#if __has_builtin(__builtin_elementwise_fma)
#define FMA2(a, b, c) __builtin_elementwise_fma((a), (b), (c))
#else
__device__ __forceinline__ f32x2 FMA2(f32x2 a, f32x2 b, f32x2 c) {
  c.x = fmaf(a.x, b.x, c.x); c.y = fmaf(a.y, b.y, c.y); return c;
}
#endif

// fast tanh: (e^2x - 1)/(e^2x + 1); v_exp_f32 is 2^x
__device__ __forceinline__ float fast_tanh(float x) {
  float xc = fminf(fmaxf(x, -10.0f), 10.0f);
  float e;
  asm("v_exp_f32 %0, %1" : "=v"(e) : "v"(xc * 2.885390081777927f)); // 2*log2(e)
  float r;
  asm("v_rcp_f32 %0, %1" : "=v"(r) : "v"(e + 1.0f));
  return (e - 1.0f) * r;
}

__device__ __forceinline__ u64 ldw(const u64* p) {
  return __hip_atomic_load(p, __ATOMIC_RELAXED, __HIP_MEMORY_SCOPE_AGENT);
}

// Weight tile: 4 j'-rows x 24 k = 96 floats/thread, 48 NAMED f32x2 scalars
// (no array -> no alloca -> register resident). gi0..gi5 are the runtime
// float4-column indices stitching the own-h block and the e-share block.
#define FORQ(M, J) M(J,0) M(J,1) M(J,2) M(J,3) M(J,4) M(J,5)
#define FORALL(M) FORQ(M,0) FORQ(M,1) FORQ(M,2) FORQ(M,3)

#define WLOAD(J,Q) float4 v##J##_##Q = wr##J[gi##Q]; \
  f32x2 wa##J##_##Q = mk2(v##J##_##Q.x, v##J##_##Q.y); \
  f32x2 wb##J##_##Q = mk2(v##J##_##Q.z, v##J##_##Q.w);
#define WPIN(J,Q) asm volatile("" : "+v"(wa##J##_##Q), "+v"(wb##J##_##Q));
#define WFMA(J,Q) acc##J = FMA2(wa##J##_##Q, mk2(cc##Q.x, cc##Q.y), acc##J); \
                  acc##J = FMA2(wb##J##_##Q, mk2(cc##Q.z, cc##Q.w), acc##J);
#define CHUNK1(J) WFMA(J,0) WFMA(J,1) WFMA(J,2)
#define CHUNK2(J) WFMA(J,3) WFMA(J,4) WFMA(J,5)

// ---------------------------------------------------------------------------
// Recurrence, own-k-slice decomposition: 256 blocks, 1024 thr. bid -> b =
// bid&63, s = bid>>6. Block s holds W[ALL 512 j'][k-slice], where the k-slice
// is exactly {own h-cols [128s,+128)} U {e-cols [64s,+64)} -> the FMA phase
// needs NO foreign data. What crosses blocks is the 512 partial sums (tagged
// 8-byte {tag,f32}, agent-scope relaxed, parity double-buffered — the proven
// R6 protocol). Consumer-side work after arrival is only sum4+bias+tanh.
// Thread: jo = tid&127 (4 j'-rows 4jo..4jo+3), kg = tid>>7 (local k
// [24kg,+24)). Local comb = 192 floats: [0..127]=own h, [128..191]=e-share.
// ---------------------------------------------------------------------------
__global__ __launch_bounds__(1024, 4) void rnn_kernel(
    const int* __restrict__ x, const float* __restrict__ hidden0,
    const float* __restrict__ emb, const float* __restrict__ Wi,
    const float* __restrict__ bi, float* __restrict__ hid_out,
    u64* __restrict__ psum)
{
  __shared__ float4 comb4[48];        // 192 floats local combined
  __shared__ float4 part4[8 * 128];   // [kg=8][j'=512] floats
  __shared__ int xrow[TT];
  float* comb = (float*)comb4;
  float* part = (float*)part4;

  const int bid = blockIdx.x;
  const int b = bid & 63, s = bid >> 6;
  const int tid = threadIdx.x;
  const int jo = tid & 127;
  const int kg = tid >> 7;

  xrow[tid] = x[b * TT + tid];
  if (tid >= 512 && tid < 640)        // comb(0) own-h slice
    comb[tid - 512] = hidden0[b * HH + s * 128 + (tid - 512)];
  if (tid >= 640 && tid < 704) {      // e(0) share; padding_idx=0 -> zeros
    int c = tid - 640;
    int idx = x[b * TT];
    comb[128 + c] = (idx != 0) ? emb[idx * EE + s * 64 + c] : 0.0f;
  }

  // weight preload: rows 4jo..4jo+3 (global j'), float4-cols gi0..gi5
  // local col4 c = kg*6+q: c<32 -> own-h col 32s+c; else e col 128+16s+(c-32)
  const int c4b = kg * 6;
  const int gi0 = (c4b + 0) < 32 ? 32 * s + (c4b + 0) : 128 + 16 * s + (c4b + 0) - 32;
  const int gi1 = (c4b + 1) < 32 ? 32 * s + (c4b + 1) : 128 + 16 * s + (c4b + 1) - 32;
  const int gi2 = (c4b + 2) < 32 ? 32 * s + (c4b + 2) : 128 + 16 * s + (c4b + 2) - 32;
  const int gi3 = (c4b + 3) < 32 ? 32 * s + (c4b + 3) : 128 + 16 * s + (c4b + 3) - 32;
  const int gi4 = (c4b + 4) < 32 ? 32 * s + (c4b + 4) : 128 + 16 * s + (c4b + 4) - 32;
  const int gi5 = (c4b + 5) < 32 ? 32 * s + (c4b + 5) : 128 + 16 * s + (c4b + 5) - 32;
  const float4* Wi4 = (const float4*)Wi;
  const float4* wr0 = Wi4 + (size_t)(jo * 4 + 0) * (KDIM / 4);
  const float4* wr1 = Wi4 + (size_t)(jo * 4 + 1) * (KDIM / 4);
  const float4* wr2 = Wi4 + (size_t)(jo * 4 + 2) * (KDIM / 4);
  const float4* wr3 = Wi4 + (size_t)(jo * 4 + 3) * (KDIM / 4);
  FORALL(WLOAD)
  FORALL(WPIN)
  const float bias = (tid >= 512 && tid < 640) ? bi[s * 128 + (tid - 512)] : 0.0f;
  __syncthreads();   // comb(0), xrow, weights ready

  const int last = TT - 1;
  const int s0 = (s + 1) & 3, s1 = (s + 2) & 3, s2 = (s + 3) & 3;

  #pragma unroll 1
  for (int i = 0; i < TT; ++i) {
    // -------- phase X: local FMA (no foreign data needed) --------
    f32x2 acc0 = mk2(0.f, 0.f), acc1 = mk2(0.f, 0.f);
    f32x2 acc2 = mk2(0.f, 0.f), acc3 = mk2(0.f, 0.f);
    const float4* cq = comb4 + kg * 6;
    {
      float4 cc0 = cq[0], cc1 = cq[1], cc2 = cq[2];
      CHUNK1(0) CHUNK1(1) CHUNK1(2) CHUNK1(3)
      float4 cc3 = cq[3], cc4 = cq[4], cc5 = cq[5];
      CHUNK2(0) CHUNK2(1) CHUNK2(2) CHUNK2(3)
    }
    part4[kg * 128 + jo] = make_float4(acc0.x + acc0.y, acc1.x + acc1.y,
                                       acc2.x + acc2.y, acc3.x + acc3.y);
    __syncthreads();   // B1: part(i) ready; comb free for step i+1 data

    // -------- phase Y --------
    const int par = (i + 1) & 1;
    u64* prow = psum + (size_t)(par * BB + b) * 2048;   // [4][512] words

    if (tid < 512) {
      // publisher: 8-way reduce + tagged publish (skip own slice — the
      // poller reads it straight from LDS)
      if ((tid >> 7) != s) {
        float p = part[tid]           + part[512 + tid]
                + part[1024 + tid]    + part[1536 + tid]
                + part[2048 + tid]    + part[2560 + tid]
                + part[3072 + tid]    + part[3584 + tid];
        u64 pv = ((u64)(unsigned)(i + 1) << 32) | __float_as_uint(p);
        __hip_atomic_store(&prow[s * 512 + tid], pv, __ATOMIC_RELAXED,
                           __HIP_MEMORY_SCOPE_AGENT);
      }
    } else if (tid < 640) {
      // poller: own partial from LDS + 3 foreign tagged words (concurrent)
      const int jloc = tid - 512;
      const int jg = s * 128 + jloc;
      float ssum = bias
                 + part[jg]           + part[512 + jg]
                 + part[1024 + jg]    + part[1536 + jg]
                 + part[2048 + jg]    + part[2560 + jg]
                 + part[3072 + jg]    + part[3584 + jg];
      const u64* p0 = &prow[s0 * 512 + jg];
      const u64* p1 = &prow[s1 * 512 + jg];
      const u64* p2 = &prow[s2 * 512 + jg];
      const unsigned tgt = (unsigned)(i + 1);
      u64 a0 = ldw(p0), a1 = ldw(p1), a2 = ldw(p2);   // 3 loads in flight
      while ((unsigned)(a0 >> 32) < tgt) a0 = ldw(p0);
      while ((unsigned)(a1 >> 32) < tgt) a1 = ldw(p1);
      while ((unsigned)(a2 >> 32) < tgt) a2 = ldw(p2);
      ssum += __uint_as_float((unsigned)a0) + __uint_as_float((unsigned)a1)
            + __uint_as_float((unsigned)a2);
      float h = fast_tanh(ssum);
      if (i == last) hid_out[b * HH + jg] = h;
      else           comb[jloc] = h;
    } else if (tid < 704 && i != last) {
      // e(i+1) share: 64 contiguous floats of the embedding row
      int c = tid - 640;
      int idx = xrow[i + 1];
      comb[128 + c] = (idx != 0) ? emb[idx * EE + s * 64 + c] : 0.0f;
    }
    __syncthreads();   // B2: comb(i+1) complete
  }
}

// ---------------------------------------------------------------------------
// Decoder: out[b][o] = sum_j h[b][j] * W_dec[o][j] + b_dec[o]
// ---------------------------------------------------------------------------
__global__ __launch_bounds__(256) void dec_kernel(
    const float* __restrict__ hid, const float* __restrict__ Wd,
    const float* __restrict__ bd, float* __restrict__ out)
{
  __shared__ float4 hl4[32 * 128];
  const int o  = blockIdx.x * 256 + threadIdx.x;
  const int b0 = blockIdx.y * 32;

  const float4* hid4 = (const float4*)(hid + b0 * HH);
  #pragma unroll
  for (int i = 0; i < 16; ++i) {
    int lin = i * 256 + threadIdx.x;
    hl4[lin] = hid4[lin];
  }
  __syncthreads();

  f32x2 acc[32];
  #pragma unroll
  for (int bb = 0; bb < 32; ++bb) acc[bb] = mk2(0.f, 0.f);

  const float4* W4 = (const float4*)(Wd + (size_t)o * HH);
  for (int j4 = 0; j4 < 128; ++j4) {
    float4 w = W4[j4];
    f32x2 wa = mk2(w.x, w.y), wb = mk2(w.z, w.w);
    #pragma unroll
    for (int bb = 0; bb < 32; ++bb) {
      float4 h = hl4[bb * 128 + j4];
      acc[bb] = FMA2(wa, mk2(h.x, h.y), acc[bb]);
      acc[bb] = FMA2(wb, mk2(h.z, h.w), acc[bb]);
    }
  }

  const float bias = bd[o];
  #pragma unroll
  for (int bb = 0; bb < 32; ++bb)
    out[(size_t)(b0 + bb) * OO + o] = acc[bb].x + acc[bb].y + bias;
}

// ---------------------------------------------------------------------------
extern "C" void kernel_launch(void* const* d_in, const int* in_sizes, int n_in,
                              void* d_out, int out_size, void* d_ws, size_t ws_size,
                              hipStream_t stream) {
  const int*   x    = (const int*)  d_in[0];   // [64][1024] int32
  const float* hid0 = (const float*)d_in[1];   // [64][512]
  const float* emb  = (const float*)d_in[2];   // [32000][256]
  const float* Wi   = (const float*)d_in[3];   // [512][768]
  const float* bi   = (const float*)d_in[4];   // [512]
  const float* Wd   = (const float*)d_in[5];   // [32000][512]
  const float* bd   = (const float*)d_in[6];   // [32000]

  float* out     = (float*)d_out;              // [64][32000]
  float* hid_out = out + (size_t)BB * OO;      // [64][512] final hidden

  u64* psum = (u64*)d_ws;                      // [2][64][4][512] tagged words

  // zero all tags every launch: graph replays repeat the same tag sequence,
  // so stale tags from the previous replay would alias (capture-legal memset)
  hipMemsetAsync(d_ws, 0, (size_t)2 * BB * 4 * HH * sizeof(u64), stream);

  rnn_kernel<<<BB * 4, 1024, 0, stream>>>(x, hid0, emb, Wi, bi, hid_out, psum);
  dec_kernel<<<dim3(OO / 256, BB / 32), 256, 0, stream>>>(hid_out, Wd, bd, out);
}

// Round 8
// 1340.935 us; speedup vs baseline: 1.4968x; 1.4968x over previous
//
#include <hip/hip_runtime.h>
#include <math.h>

// Problem dims (fixed by the reference)
#define BB 64
#define TT 1024
#define EE 256
#define HH 512
#define OO 32000
#define KDIM 768   // H+E

typedef float f32x2 __attribute__((ext_vector_type(2)));
typedef unsigned long long u64;

__device__ __forceinline__ f32x2 mk2(float a, float b) { f32x2 r; r.x = a; r.y = b; return r; }

#if __has_builtin(__builtin_elementwise_fma)
#define FMA2(a, b, c) __builtin_elementwise_fma((a), (b), (c))
#else
__device__ __forceinline__ f32x2 FMA2(f32x2 a, f32x2 b, f32x2 c) {
  c.x = fmaf(a.x, b.x, c.x); c.y = fmaf(a.y, b.y, c.y); return c;
}
#endif

// fast tanh: (e^2x - 1)/(e^2x + 1); v_exp_f32 is 2^x
__device__ __forceinline__ float fast_tanh(float x) {
  float xc = fminf(fmaxf(x, -10.0f), 10.0f);
  float e;
  asm("v_exp_f32 %0, %1" : "=v"(e) : "v"(xc * 2.885390081777927f)); // 2*log2(e)
  float r;
  asm("v_rcp_f32 %0, %1" : "=v"(r) : "v"(e + 1.0f));
  return (e - 1.0f) * r;
}

__device__ __forceinline__ u64 ldw(const u64* p) {
  return __hip_atomic_load(p, __ATOMIC_RELAXED, __HIP_MEMORY_SCOPE_AGENT);
}

// Weight tile: 4 j-rows x 24 k-cols = 96 floats/thread, 48 NAMED f32x2
// scalars (no array -> no alloca -> register resident). gi0..gi5 are runtime
// float4-column indices (local role: own-h/e stitched; foreign role: the
// 3 sibling h-slices with own range skipped).
#define FORQ(M, J) M(J,0) M(J,1) M(J,2) M(J,3) M(J,4) M(J,5)
#define FORALL(M) FORQ(M,0) FORQ(M,1) FORQ(M,2) FORQ(M,3)

#define WLOAD(J,Q) float4 v##J##_##Q = wr##J[gi##Q]; \
  f32x2 wa##J##_##Q = mk2(v##J##_##Q.x, v##J##_##Q.y); \
  f32x2 wb##J##_##Q = mk2(v##J##_##Q.z, v##J##_##Q.w);
#define WPIN(J,Q) asm volatile("" : "+v"(wa##J##_##Q), "+v"(wb##J##_##Q));
#define WFMA(J,Q) acc##J = FMA2(wa##J##_##Q, mk2(cc##Q.x, cc##Q.y), acc##J); \
                  acc##J = FMA2(wb##J##_##Q, mk2(cc##Q.z, cc##Q.w), acc##J);
#define CHUNK1(J) WFMA(J,0) WFMA(J,1) WFMA(J,2)
#define CHUNK2(J) WFMA(J,3) WFMA(J,4) WFMA(J,5)

// ---------------------------------------------------------------------------
// Recurrence: 256 blocks, 1024 thr. bid -> b = bid&63, s = bid>>6. Block owns
// output rows j in [128s,+128), all 768 k. k re-partitioned by locality:
//   kg 0..15  (tid<512,  waves 0-7)  = LOCAL cols {own-h 128, e 256}
//   kg 16..31 (tid>=512, waves 8-15) = FOREIGN cols (3 sibling h-slices)
// Step schedule (3 unconditional barriers):
//   pre-B_mid : waves0-7 local-FMA | waves8-13 poll 384 tagged words -> LDS
//               | thr896-959 prefetch e(i+1) (double-buffered e slot)
//   post-B_mid: waves8-15 foreign-FMA | thr0-127 early-reduce local partials
//   post-B1   : thr0-127 final reduce + tanh + publish tag i+1 ; B2
// Cross-block exchange = R6's proven tagged {u32 tag, f32 h} parity-double-
// buffered agent-scope protocol (128 publishes/block/step). h(0) foreign is
// preloaded from hidden0, so step 0 never polls.
// ---------------------------------------------------------------------------
__global__ __launch_bounds__(1024, 4) void rnn_kernel(
    const int* __restrict__ x, const float* __restrict__ hidden0,
    const float* __restrict__ emb, const float* __restrict__ Wi,
    const float* __restrict__ bi, float* __restrict__ hid_out,
    u64* __restrict__ psum)
{
  // comb float4 map: [0,32)=own-h, [32,96)=eA, [96,160)=eB, [160,256)=foreign-h
  __shared__ float4 comb4[256];
  __shared__ float4 part4[32 * 32];   // [kg=32][j=128] floats
  __shared__ float part2[128];
  __shared__ int xrow[TT];
  float* comb = (float*)comb4;
  float* part = (float*)part4;

  const int bid = blockIdx.x;
  const int b = bid & 63, s = bid >> 6;
  const int tid = threadIdx.x;
  const int jo = tid & 31;
  const int kg = tid >> 5;            // 0..31
  const bool isLocal = (tid < 512);

  xrow[tid] = x[b * TT + tid];

  // h(0): own 128 -> comb[0..128); foreign 384 -> comb[640..1024)
  if (tid < HH) {
    int j = tid;
    float v = hidden0[b * HH + j];
    int addr = ((j >> 7) == s) ? (j - 128 * s)
                               : (640 + (j < 128 * s ? j : j - 128));
    comb[addr] = v;
  }
  if (tid >= 896 && tid < 960) {      // e(0) -> ebuf0; padding_idx=0 -> zeros
    int t = tid - 896;
    int idx = x[b * TT];
    float4 e0 = make_float4(0.f, 0.f, 0.f, 0.f);
    if (idx != 0) e0 = ((const float4*)emb)[idx * (EE / 4) + t];
    comb4[32 + t] = e0;
  }

  // ---- weight preload: rows 128s+4jo+J, role-dependent f4 columns ----
  const int c4b = 6 * (isLocal ? kg : (kg - 16));
  const int t32s = 32 * s;
  const int c4_0 = c4b + 0, c4_1 = c4b + 1, c4_2 = c4b + 2;
  const int c4_3 = c4b + 3, c4_4 = c4b + 4, c4_5 = c4b + 5;
  // local: c4<32 -> own-h f4 (32s+c4); c4>=32 -> e f4 (96+c4). foreign: skip own.
  const int gi0 = isLocal ? (c4_0 < 32 ? t32s + c4_0 : 96 + c4_0) : (c4_0 + (c4_0 >= t32s ? 32 : 0));
  const int gi1 = isLocal ? (c4_1 < 32 ? t32s + c4_1 : 96 + c4_1) : (c4_1 + (c4_1 >= t32s ? 32 : 0));
  const int gi2 = isLocal ? (c4_2 < 32 ? t32s + c4_2 : 96 + c4_2) : (c4_2 + (c4_2 >= t32s ? 32 : 0));
  const int gi3 = isLocal ? (c4_3 < 32 ? t32s + c4_3 : 96 + c4_3) : (c4_3 + (c4_3 >= t32s ? 32 : 0));
  const int gi4 = isLocal ? (c4_4 < 32 ? t32s + c4_4 : 96 + c4_4) : (c4_4 + (c4_4 >= t32s ? 32 : 0));
  const int gi5 = isLocal ? (c4_5 < 32 ? t32s + c4_5 : 96 + c4_5) : (c4_5 + (c4_5 >= t32s ? 32 : 0));
  const float4* Wi4 = (const float4*)Wi;
  const float4* wr0 = Wi4 + (size_t)(s * 128 + jo * 4 + 0) * (KDIM / 4);
  const float4* wr1 = wr0 + (KDIM / 4);
  const float4* wr2 = wr1 + (KDIM / 4);
  const float4* wr3 = wr2 + (KDIM / 4);
  FORALL(WLOAD)
  FORALL(WPIN)
  const float bias = (tid < 128) ? bi[s * 128 + tid] : 0.0f;
  __syncthreads();   // comb(0), xrow, weights ready

  const int last = TT - 1;

  #pragma unroll 1
  for (int i = 0; i < TT; ++i) {
    const int ebuf = i & 1;
    // ---------------- pre-B_mid ----------------
    if (isLocal) {
      // local FMA over {own-h(i), e(i)}; e sits at +64 f4 when ebuf==1
      const int eo = ebuf * 64;
      const int a0 = c4_0 + (c4_0 >= 32 ? eo : 0);
      const int a1 = c4_1 + (c4_1 >= 32 ? eo : 0);
      const int a2 = c4_2 + (c4_2 >= 32 ? eo : 0);
      const int a3 = c4_3 + (c4_3 >= 32 ? eo : 0);
      const int a4 = c4_4 + (c4_4 >= 32 ? eo : 0);
      const int a5 = c4_5 + (c4_5 >= 32 ? eo : 0);
      f32x2 acc0 = mk2(0.f, 0.f), acc1 = mk2(0.f, 0.f);
      f32x2 acc2 = mk2(0.f, 0.f), acc3 = mk2(0.f, 0.f);
      {
        float4 cc0 = comb4[a0], cc1 = comb4[a1], cc2 = comb4[a2];
        CHUNK1(0) CHUNK1(1) CHUNK1(2) CHUNK1(3)
        float4 cc3 = comb4[a3], cc4 = comb4[a4], cc5 = comb4[a5];
        CHUNK2(0) CHUNK2(1) CHUNK2(2) CHUNK2(3)
      }
      part4[kg * 32 + jo] = make_float4(acc0.x + acc0.y, acc1.x + acc1.y,
                                        acc2.x + acc2.y, acc3.x + acc3.y);
    } else {
      const int r = tid - 512;
      if (r < 384) {
        if (i > 0) {
          // poll one tagged foreign word (h(i), tag i, parity i&1)
          const int fj = r + (r >= 128 * s ? 128 : 0);
          const u64* pw = psum + (size_t)(ebuf * BB + b) * HH + fj;
          const unsigned tgt = (unsigned)i;
          u64 v = ldw(pw);
          while ((unsigned)(v >> 32) < tgt) v = ldw(pw);
          comb[640 + r] = __uint_as_float((unsigned)v);
        }
      } else if (r < 448 && i != last) {
        // e(i+1) prefetch into the other e slot
        int t = r - 384;
        int idx = xrow[i + 1];
        float4 e4 = make_float4(0.f, 0.f, 0.f, 0.f);
        if (idx != 0) e4 = ((const float4*)emb)[idx * (EE / 4) + t];
        comb4[32 + (ebuf ^ 1) * 64 + t] = e4;
      }
    }
    __syncthreads();   // B_mid: foreign-h(i) + part[0..15] in LDS

    // ---------------- post-B_mid ----------------
    if (!isLocal) {
      // foreign FMA over comb[640..1024)
      f32x2 acc0 = mk2(0.f, 0.f), acc1 = mk2(0.f, 0.f);
      f32x2 acc2 = mk2(0.f, 0.f), acc3 = mk2(0.f, 0.f);
      {
        float4 cc0 = comb4[160 + c4_0], cc1 = comb4[160 + c4_1], cc2 = comb4[160 + c4_2];
        CHUNK1(0) CHUNK1(1) CHUNK1(2) CHUNK1(3)
        float4 cc3 = comb4[160 + c4_3], cc4 = comb4[160 + c4_4], cc5 = comb4[160 + c4_5];
        CHUNK2(0) CHUNK2(1) CHUNK2(2) CHUNK2(3)
      }
      part4[kg * 32 + jo] = make_float4(acc0.x + acc0.y, acc1.x + acc1.y,
                                        acc2.x + acc2.y, acc3.x + acc3.y);
    } else if (tid < 128) {
      // early-reduce the 16 local partials (runs parallel with foreign FMA)
      float ssum = part[0 * 128 + tid] + part[1 * 128 + tid]
                 + part[2 * 128 + tid] + part[3 * 128 + tid]
                 + part[4 * 128 + tid] + part[5 * 128 + tid]
                 + part[6 * 128 + tid] + part[7 * 128 + tid]
                 + part[8 * 128 + tid] + part[9 * 128 + tid]
                 + part[10 * 128 + tid] + part[11 * 128 + tid]
                 + part[12 * 128 + tid] + part[13 * 128 + tid]
                 + part[14 * 128 + tid] + part[15 * 128 + tid];
      part2[tid] = ssum;
    }
    __syncthreads();   // B1: all 32 partials ready

    // ---------------- post-B1 ----------------
    if (tid < 128) {
      float ssum = bias + part2[tid]
                 + part[16 * 128 + tid] + part[17 * 128 + tid]
                 + part[18 * 128 + tid] + part[19 * 128 + tid]
                 + part[20 * 128 + tid] + part[21 * 128 + tid]
                 + part[22 * 128 + tid] + part[23 * 128 + tid]
                 + part[24 * 128 + tid] + part[25 * 128 + tid]
                 + part[26 * 128 + tid] + part[27 * 128 + tid]
                 + part[28 * 128 + tid] + part[29 * 128 + tid]
                 + part[30 * 128 + tid] + part[31 * 128 + tid];
      float h = fast_tanh(ssum);
      if (i == last) {
        hid_out[b * HH + s * 128 + tid] = h;
      } else {
        comb[tid] = h;   // own-h for step i+1
        u64 pv = ((u64)(unsigned)(i + 1) << 32) | __float_as_uint(h);
        __hip_atomic_store(psum + (size_t)(((i + 1) & 1) * BB + b) * HH
                               + (s * 128 + tid),
                           pv, __ATOMIC_RELAXED, __HIP_MEMORY_SCOPE_AGENT);
      }
    }
    __syncthreads();   // B2: comb own-h(i+1) in place; next step may proceed
  }
}

// ---------------------------------------------------------------------------
// Decoder: out[b][o] = sum_j h[b][j] * W_dec[o][j] + b_dec[o]
// ---------------------------------------------------------------------------
__global__ __launch_bounds__(256) void dec_kernel(
    const float* __restrict__ hid, const float* __restrict__ Wd,
    const float* __restrict__ bd, float* __restrict__ out)
{
  __shared__ float4 hl4[32 * 128];
  const int o  = blockIdx.x * 256 + threadIdx.x;
  const int b0 = blockIdx.y * 32;

  const float4* hid4 = (const float4*)(hid + b0 * HH);
  #pragma unroll
  for (int i = 0; i < 16; ++i) {
    int lin = i * 256 + threadIdx.x;
    hl4[lin] = hid4[lin];
  }
  __syncthreads();

  f32x2 acc[32];
  #pragma unroll
  for (int bb = 0; bb < 32; ++bb) acc[bb] = mk2(0.f, 0.f);

  const float4* W4 = (const float4*)(Wd + (size_t)o * HH);
  for (int j4 = 0; j4 < 128; ++j4) {
    float4 w = W4[j4];
    f32x2 wa = mk2(w.x, w.y), wb = mk2(w.z, w.w);
    #pragma unroll
    for (int bb = 0; bb < 32; ++bb) {
      float4 h = hl4[bb * 128 + j4];
      acc[bb] = FMA2(wa, mk2(h.x, h.y), acc[bb]);
      acc[bb] = FMA2(wb, mk2(h.z, h.w), acc[bb]);
    }
  }

  const float bias = bd[o];
  #pragma unroll
  for (int bb = 0; bb < 32; ++bb)
    out[(size_t)(b0 + bb) * OO + o] = acc[bb].x + acc[bb].y + bias;
}

// ---------------------------------------------------------------------------
extern "C" void kernel_launch(void* const* d_in, const int* in_sizes, int n_in,
                              void* d_out, int out_size, void* d_ws, size_t ws_size,
                              hipStream_t stream) {
  const int*   x    = (const int*)  d_in[0];   // [64][1024] int32
  const float* hid0 = (const float*)d_in[1];   // [64][512]
  const float* emb  = (const float*)d_in[2];   // [32000][256]
  const float* Wi   = (const float*)d_in[3];   // [512][768]
  const float* bi   = (const float*)d_in[4];   // [512]
  const float* Wd   = (const float*)d_in[5];   // [32000][512]
  const float* bd   = (const float*)d_in[6];   // [32000]

  float* out     = (float*)d_out;              // [64][32000]
  float* hid_out = out + (size_t)BB * OO;      // [64][512] final hidden

  u64* psum = (u64*)d_ws;                      // [2][64][512] tagged words

  // zero all tags every launch: graph replays repeat the same tag sequence,
  // so stale tags from the previous replay would alias (capture-legal memset)
  hipMemsetAsync(d_ws, 0, (size_t)2 * BB * HH * sizeof(u64), stream);

  rnn_kernel<<<BB * 4, 1024, 0, stream>>>(x, hid0, emb, Wi, bi, hid_out, psum);
  dec_kernel<<<dim3(OO / 256, BB / 32), 256, 0, stream>>>(hid_out, Wd, bd, out);
}